// Round 1
// baseline (2491.070 us; speedup 1.0000x reference)
//
#include <hip/hip_runtime.h>
#include <hip/hip_bf16.h>
#include <stdint.h>

#define NN 100000
#define NE 600000
#define ND 128
#define ED 32
#define HID 128

// ---------- bf16 helpers (manual RNE, deterministic) ----------
__device__ __forceinline__ uint32_t f2bf(float f) {
  uint32_t u = __float_as_uint(f);
  return (u + 0x7FFFu + ((u >> 16) & 1u)) >> 16;
}
__device__ __forceinline__ float bf2f(uint32_t h) {
  return __uint_as_float(h << 16);
}

// ---------- shared GEMM tile: 64 rows x 128 cols, thread tile 4x8 ----------
// sA_ points at a [64][LDA] fp32 LDS tile (row-padded); Wc is global [KK][128].
template <int KK, int LDA>
__device__ __forceinline__ void gemm_chunk(float acc[4][8], const float* sA_,
                                           const float* __restrict__ Wc,
                                           int eg, int j0) {
#pragma unroll
  for (int kk = 0; kk < KK; kk += 4) {
    float4 a[4];
#pragma unroll
    for (int i = 0; i < 4; ++i)
      a[i] = *(const float4*)&sA_[(eg * 4 + i) * LDA + kk];
#pragma unroll
    for (int r = 0; r < 4; ++r) {
      float4 w0 = *(const float4*)(Wc + (kk + r) * HID + j0);
      float4 w1 = *(const float4*)(Wc + (kk + r) * HID + j0 + 4);
#pragma unroll
      for (int i = 0; i < 4; ++i) {
        float av = (r == 0) ? a[i].x : (r == 1) ? a[i].y : (r == 2) ? a[i].z : a[i].w;
        acc[i][0] += av * w0.x; acc[i][1] += av * w0.y;
        acc[i][2] += av * w0.z; acc[i][3] += av * w0.w;
        acc[i][4] += av * w1.x; acc[i][5] += av * w1.y;
        acc[i][6] += av * w1.z; acc[i][7] += av * w1.w;
      }
    }
  }
}

__device__ __forceinline__ void init_bias(float acc[4][8], const float* __restrict__ b, int j0) {
  float4 bA = *(const float4*)(b + j0);
  float4 bB = *(const float4*)(b + j0 + 4);
#pragma unroll
  for (int i = 0; i < 4; ++i) {
    acc[i][0] = bA.x; acc[i][1] = bA.y; acc[i][2] = bA.z; acc[i][3] = bA.w;
    acc[i][4] = bB.x; acc[i][5] = bB.y; acc[i][6] = bB.z; acc[i][7] = bB.w;
  }
}

// ---------- edge MLP: messages (bf16) + attention logits ----------
__global__ __launch_bounds__(256) void k_edge_mlp(
    const float* __restrict__ nf, const float* __restrict__ ef,
    const float* __restrict__ W1, const float* __restrict__ b1,
    const float* __restrict__ W2, const float* __restrict__ b2,
    const float* __restrict__ aW, const int* __restrict__ ei,
    uint16_t* __restrict__ msg, float* __restrict__ logits) {
  __shared__ float sA[64 * 36];    // 32-wide K chunk, pad 36 (16B-aligned rows)
  __shared__ float sH[64 * 132];   // hidden tile, pad 132
  __shared__ int sIdx[128];        // row[64] | col[64]

  const int tid = threadIdx.x;
  const int e0 = blockIdx.x * 64;
  const int jg = tid & 15, eg = tid >> 4;
  const int j0 = jg * 8;

  if (tid < 64) {
    sIdx[tid] = ei[e0 + tid];
    sIdx[64 + tid] = ei[NE + e0 + tid];
  }

  float acc[4][8];
  init_bias(acc, b1, j0);
  __syncthreads();

  // layer 1: K = 288 = 9 chunks of 32.  chunks 0-3: nf[row], 4-7: nf[col], 8: ef
  for (int c = 0; c < 9; ++c) {
    for (int t = tid; t < 512; t += 256) {
      int e = t >> 3, k4 = (t & 7) * 4;
      const float* src;
      if (c < 4)      src = nf + (size_t)sIdx[e] * ND + c * 32 + k4;
      else if (c < 8) src = nf + (size_t)sIdx[64 + e] * ND + (c - 4) * 32 + k4;
      else            src = ef + (size_t)(e0 + e) * ED + k4;
      *(float4*)&sA[e * 36 + k4] = *(const float4*)src;
    }
    __syncthreads();
    gemm_chunk<32, 36>(acc, sA, W1 + c * 32 * HID, eg, j0);
    __syncthreads();
  }

  // relu -> sH
#pragma unroll
  for (int i = 0; i < 4; ++i) {
    int e = eg * 4 + i;
    float4 h0, h1;
    h0.x = fmaxf(acc[i][0], 0.f); h0.y = fmaxf(acc[i][1], 0.f);
    h0.z = fmaxf(acc[i][2], 0.f); h0.w = fmaxf(acc[i][3], 0.f);
    h1.x = fmaxf(acc[i][4], 0.f); h1.y = fmaxf(acc[i][5], 0.f);
    h1.z = fmaxf(acc[i][6], 0.f); h1.w = fmaxf(acc[i][7], 0.f);
    *(float4*)&sH[e * 132 + j0] = h0;
    *(float4*)&sH[e * 132 + j0 + 4] = h1;
  }
  __syncthreads();

  // layer 2: K = 128 in 4 chunks (limits unroll / I-cache)
  float acc2[4][8];
  init_bias(acc2, b2, j0);
  for (int c2 = 0; c2 < 4; ++c2)
    gemm_chunk<32, 132>(acc2, sH + c2 * 32, W2 + c2 * 32 * HID, eg, j0);

  // attention logit partial (reduce across the 16 jg lanes) + bf16 message write
  float4 awA = *(const float4*)(aW + j0);
  float4 awB = *(const float4*)(aW + j0 + 4);
#pragma unroll
  for (int i = 0; i < 4; ++i) {
    int e = e0 + eg * 4 + i;
    float p = acc2[i][0] * awA.x + acc2[i][1] * awA.y + acc2[i][2] * awA.z +
              acc2[i][3] * awA.w + acc2[i][4] * awB.x + acc2[i][5] * awB.y +
              acc2[i][6] * awB.z + acc2[i][7] * awB.w;
#pragma unroll
    for (int s = 1; s < 16; s <<= 1) p += __shfl_xor(p, s, 64);
    if (jg == 0) logits[e] = p;  // a_b omitted: softmax is shift-invariant
    uint32_t pk[4];
#pragma unroll
    for (int q = 0; q < 4; ++q)
      pk[q] = f2bf(acc2[i][2 * q]) | (f2bf(acc2[i][2 * q + 1]) << 16);
    *(uint4*)(msg + (size_t)e * HID + j0) = make_uint4(pk[0], pk[1], pk[2], pk[3]);
  }
}

// ---------- softmax reductions ----------
__device__ __forceinline__ float block_reduce_max(float m) {
#pragma unroll
  for (int s = 1; s < 64; s <<= 1) m = fmaxf(m, __shfl_xor(m, s, 64));
  __shared__ float sm[4];
  if ((threadIdx.x & 63) == 0) sm[threadIdx.x >> 6] = m;
  __syncthreads();
  return fmaxf(fmaxf(sm[0], sm[1]), fmaxf(sm[2], sm[3]));
}
__device__ __forceinline__ float block_reduce_sum(float v) {
#pragma unroll
  for (int s = 1; s < 64; s <<= 1) v += __shfl_xor(v, s, 64);
  __shared__ float sv[4];
  if ((threadIdx.x & 63) == 0) sv[threadIdx.x >> 6] = v;
  __syncthreads();
  return sv[0] + sv[1] + sv[2] + sv[3];
}

__global__ __launch_bounds__(256) void k_redmax_p(const float* __restrict__ logits,
                                                 float* __restrict__ pmax) {
  float m = -3.402823466e38f;
  for (int i = blockIdx.x * 256 + threadIdx.x; i < NE; i += 1024 * 256)
    m = fmaxf(m, logits[i]);
  m = block_reduce_max(m);
  if (threadIdx.x == 0) pmax[blockIdx.x] = m;
}
__global__ __launch_bounds__(256) void k_redmax_f(const float* __restrict__ p,
                                                 float* __restrict__ red) {
  float m = fmaxf(fmaxf(p[threadIdx.x], p[threadIdx.x + 256]),
                  fmaxf(p[threadIdx.x + 512], p[threadIdx.x + 768]));
  m = block_reduce_max(m);
  if (threadIdx.x == 0) red[0] = m;
}
__global__ __launch_bounds__(256) void k_redsum_p(const float* __restrict__ logits,
                                                 const float* __restrict__ red,
                                                 float* __restrict__ psum) {
  float gm = red[0], s = 0.f;
  for (int i = blockIdx.x * 256 + threadIdx.x; i < NE; i += 1024 * 256)
    s += expf(logits[i] - gm);
  s = block_reduce_sum(s);
  if (threadIdx.x == 0) psum[blockIdx.x] = s;
}
__global__ __launch_bounds__(256) void k_redsum_f(const float* __restrict__ p,
                                                 float* __restrict__ red) {
  float s = p[threadIdx.x] + p[threadIdx.x + 256] + p[threadIdx.x + 512] +
            p[threadIdx.x + 768];
  s = block_reduce_sum(s);
  if (threadIdx.x == 0) red[1] = 1.0f / s;
}

// ---------- attn-weighted scatter-add into d_out ----------
__global__ __launch_bounds__(256) void k_scatter(
    const uint16_t* __restrict__ msg, const float* __restrict__ logits,
    const int* __restrict__ ei, const float* __restrict__ red,
    float* __restrict__ agg) {
  int gid = blockIdx.x * 256 + threadIdx.x;
  int e = gid >> 5, q = (gid & 31) * 4;
  if (e >= NE) return;
  float w = expf(logits[e] - red[0]) * red[1];
  int c = ei[NE + e];
  ushort4 m4 = *(const ushort4*)(msg + (size_t)e * HID + q);
  float* dst = agg + (size_t)c * ND + q;
  atomicAdd(dst + 0, w * bf2f(m4.x));
  atomicAdd(dst + 1, w * bf2f(m4.y));
  atomicAdd(dst + 2, w * bf2f(m4.z));
  atomicAdd(dst + 3, w * bf2f(m4.w));
}

// ---------- node update MLP (+ residual), in-place on d_out ----------
__global__ __launch_bounds__(256) void k_node_update(
    const float* __restrict__ nf, const float* __restrict__ agg,
    const float* __restrict__ W1, const float* __restrict__ b1,
    const float* __restrict__ W2, const float* __restrict__ b2,
    float* __restrict__ out) {
  __shared__ float sA[64 * 36];
  __shared__ float sH[64 * 132];
  const int tid = threadIdx.x;
  const int n0 = blockIdx.x * 64;
  const int jg = tid & 15, eg = tid >> 4;
  const int j0 = jg * 8;

  float acc[4][8];
  init_bias(acc, b1, j0);

  // layer 1: K = 256 = 8 chunks. chunks 0-3: nf, 4-7: agg (== d_out, read-before-write
  // is safe: each block only touches its own 64 rows, all reads precede all writes)
  for (int c = 0; c < 8; ++c) {
    for (int t = tid; t < 512; t += 256) {
      int e = t >> 3, k4 = (t & 7) * 4;
      int n = n0 + e; if (n >= NN) n = NN - 1;
      const float* src = (c < 4) ? nf + (size_t)n * ND + c * 32 + k4
                                 : agg + (size_t)n * ND + (c - 4) * 32 + k4;
      *(float4*)&sA[e * 36 + k4] = *(const float4*)src;
    }
    __syncthreads();
    gemm_chunk<32, 36>(acc, sA, W1 + c * 32 * HID, eg, j0);
    __syncthreads();
  }

#pragma unroll
  for (int i = 0; i < 4; ++i) {
    int e = eg * 4 + i;
    float4 h0, h1;
    h0.x = fmaxf(acc[i][0], 0.f); h0.y = fmaxf(acc[i][1], 0.f);
    h0.z = fmaxf(acc[i][2], 0.f); h0.w = fmaxf(acc[i][3], 0.f);
    h1.x = fmaxf(acc[i][4], 0.f); h1.y = fmaxf(acc[i][5], 0.f);
    h1.z = fmaxf(acc[i][6], 0.f); h1.w = fmaxf(acc[i][7], 0.f);
    *(float4*)&sH[e * 132 + j0] = h0;
    *(float4*)&sH[e * 132 + j0 + 4] = h1;
  }
  __syncthreads();

  float acc2[4][8];
  init_bias(acc2, b2, j0);
  for (int c2 = 0; c2 < 4; ++c2)
    gemm_chunk<32, 132>(acc2, sH + c2 * 32, W2 + c2 * 32 * HID, eg, j0);

  // residual + store
#pragma unroll
  for (int i = 0; i < 4; ++i) {
    int n = n0 + eg * 4 + i;
    if (n < NN) {
      float4 r0 = *(const float4*)(nf + (size_t)n * ND + j0);
      float4 r1 = *(const float4*)(nf + (size_t)n * ND + j0 + 4);
      float4 o0, o1;
      o0.x = acc2[i][0] + r0.x; o0.y = acc2[i][1] + r0.y;
      o0.z = acc2[i][2] + r0.z; o0.w = acc2[i][3] + r0.w;
      o1.x = acc2[i][4] + r1.x; o1.y = acc2[i][5] + r1.y;
      o1.z = acc2[i][6] + r1.z; o1.w = acc2[i][7] + r1.w;
      *(float4*)(out + (size_t)n * ND + j0) = o0;
      *(float4*)(out + (size_t)n * ND + j0 + 4) = o1;
    }
  }
}

__global__ __launch_bounds__(256) void k_zero(float4* __restrict__ p, int n4) {
  for (int i = blockIdx.x * 256 + threadIdx.x; i < n4; i += gridDim.x * 256)
    p[i] = make_float4(0.f, 0.f, 0.f, 0.f);
}

extern "C" void kernel_launch(void* const* d_in, const int* in_sizes, int n_in,
                              void* d_out, int out_size, void* d_ws, size_t ws_size,
                              hipStream_t stream) {
  const float* nf  = (const float*)d_in[0];
  const float* ef  = (const float*)d_in[1];
  const float* mW1 = (const float*)d_in[2];
  const float* mb1 = (const float*)d_in[3];
  const float* mW2 = (const float*)d_in[4];
  const float* mb2 = (const float*)d_in[5];
  const float* aW  = (const float*)d_in[6];
  // d_in[7] = a_b — unused (softmax is invariant to a constant logit shift)
  const float* uW1 = (const float*)d_in[8];
  const float* ub1 = (const float*)d_in[9];
  const float* uW2 = (const float*)d_in[10];
  const float* ub2 = (const float*)d_in[11];
  const int*   ei  = (const int*)d_in[12];
  float* out = (float*)d_out;

  // workspace: msg bf16 [NE*128] (153.6MB) | logits f32 [NE] | pmax[1024] | psum[1024] | red[2]
  char* ws = (char*)d_ws;
  uint16_t* msg = (uint16_t*)ws;
  float* logits = (float*)(ws + (size_t)NE * HID * 2);
  float* pmax = logits + NE;
  float* psum = pmax + 1024;
  float* red  = psum + 1024;

  k_zero<<<2048, 256, 0, stream>>>((float4*)out, NN * ND / 4);
  k_edge_mlp<<<NE / 64, 256, 0, stream>>>(nf, ef, mW1, mb1, mW2, mb2, aW, ei, msg, logits);
  k_redmax_p<<<1024, 256, 0, stream>>>(logits, pmax);
  k_redmax_f<<<1, 256, 0, stream>>>(pmax, red);
  k_redsum_p<<<1024, 256, 0, stream>>>(logits, red, psum);
  k_redsum_f<<<1, 256, 0, stream>>>(psum, red);
  k_scatter<<<(NE * 32) / 256, 256, 0, stream>>>(msg, logits, ei, red, out);
  k_node_update<<<(NN + 63) / 64, 256, 0, stream>>>(nf, out, uW1, ub1, uW2, ub2, out);
}

// Round 4
// 1255.665 us; speedup vs baseline: 1.9839x; 1.9839x over previous
//
#include <hip/hip_runtime.h>
#include <hip/hip_bf16.h>
#include <stdint.h>

#define NN 100000
#define NE 600000
#define ND 128
#define ED 32
#define HID 128

using short8 = __attribute__((ext_vector_type(8))) short;
using f32x4  = __attribute__((ext_vector_type(4))) float;

// ---------- bf16 helpers (manual RNE, deterministic) ----------
__device__ __forceinline__ uint32_t f2bf(float f) {
  uint32_t u = __float_as_uint(f);
  return (u + 0x7FFFu + ((u >> 16) & 1u)) >> 16;
}
__device__ __forceinline__ float bf2f(uint32_t h) {
  return __uint_as_float(h << 16);
}

// ---------- weight pre-pack: frag-ordered bf16 ----------
// layout: for chunk c (K/32), tile nt (N/16), group g (0..3), col c16 (0..15),
// j (0..7): W[c*32+g*8+j][nt*16+c16].  8KB per K-chunk, contiguous.
__global__ __launch_bounds__(256) void k_prep(
    const float* __restrict__ W1, const float* __restrict__ W2,
    const float* __restrict__ uW1, const float* __restrict__ uW2,
    short* __restrict__ W1p, short* __restrict__ W2p,
    short* __restrict__ U1p, short* __restrict__ U2p) {
  int o = blockIdx.x * 256 + threadIdx.x;
  const float* src; short* dst; int rel;
  if (o < 36864)      { rel = o;         src = W1;  dst = W1p; }
  else if (o < 53248) { rel = o - 36864; src = W2;  dst = W2p; }
  else if (o < 86016) { rel = o - 53248; src = uW1; dst = U1p; }
  else                { rel = o - 86016; src = uW2; dst = U2p; }
  int j = rel & 7, c16 = (rel >> 3) & 15, g = (rel >> 7) & 3, nt = (rel >> 9) & 7, c = rel >> 12;
  int k = c * 32 + g * 8 + j, n = nt * 16 + c16;
  dst[rel] = (short)f2bf(src[k * 128 + n]);
}

// ---------- edge MLP via MFMA: messages (bf16) + attention logits ----------
__global__ __launch_bounds__(256, 2) void k_edge_mfma(
    const float* __restrict__ nf, const float* __restrict__ ef,
    const short* __restrict__ W1p, const float* __restrict__ b1,
    const short* __restrict__ W2p, const float* __restrict__ b2,
    const float* __restrict__ aW, const int* __restrict__ ei,
    uint16_t* __restrict__ msg, float* __restrict__ logits) {
  __shared__ __align__(16) short sA[192 * 40];   // A chunk: [192 rows][32k] pitch 40
  __shared__ __align__(16) short sB[4096];       // B chunk: frag-ordered 32x128
  __shared__ __align__(16) short sH[192 * 136];  // hidden [192][128] pitch 136
  __shared__ int sIdx[384];

  const int tid = threadIdx.x;
  const int wv = tid >> 6, ln = tid & 63, cr = ln & 15, gp = ln >> 4;
  const int e0 = blockIdx.x * 192;
  const int wrow = wv * 48;

  if (tid < 192) {
    sIdx[tid] = ei[e0 + tid];
    sIdx[192 + tid] = ei[NE + e0 + tid];
  }

  float bia[8], aWr[8], bia2[8];
#pragma unroll
  for (int nt = 0; nt < 8; ++nt) {
    bia[nt] = b1[nt * 16 + cr];
    bia2[nt] = b2[nt * 16 + cr];
    aWr[nt] = aW[nt * 16 + cr];
  }
  f32x4 acc[3][8];
#pragma unroll
  for (int mt = 0; mt < 3; ++mt)
#pragma unroll
    for (int nt = 0; nt < 8; ++nt)
      acc[mt][nt] = (f32x4){bia[nt], bia[nt], bia[nt], bia[nt]};
  __syncthreads();

  // ---- layer 1: K = 288 (chunks 0-3: nf[row], 4-7: nf[col], 8: ef) ----
  for (int c = 0; c < 9; ++c) {
#pragma unroll
    for (int it = 0; it < 3; ++it) {
      int row = it * 64 + (tid >> 2), k8 = (tid & 3) * 8;
      const float* src;
      if (c < 4)      src = nf + (size_t)sIdx[row] * ND + c * 32 + k8;
      else if (c < 8) src = nf + (size_t)sIdx[192 + row] * ND + (c - 4) * 32 + k8;
      else            src = ef + (size_t)(e0 + row) * ED + k8;
      float4 v0 = *(const float4*)src, v1 = *(const float4*)(src + 4);
      short8 s;
      s[0] = (short)f2bf(v0.x); s[1] = (short)f2bf(v0.y);
      s[2] = (short)f2bf(v0.z); s[3] = (short)f2bf(v0.w);
      s[4] = (short)f2bf(v1.x); s[5] = (short)f2bf(v1.y);
      s[6] = (short)f2bf(v1.z); s[7] = (short)f2bf(v1.w);
      *(short8*)&sA[row * 40 + k8] = s;
    }
    {
      const short8* wsrc = (const short8*)(W1p + c * 4096);
      short8 t0 = wsrc[tid], t1 = wsrc[tid + 256];
      ((short8*)sB)[tid] = t0; ((short8*)sB)[tid + 256] = t1;
    }
    __syncthreads();
    short8 af[3];
#pragma unroll
    for (int mt = 0; mt < 3; ++mt)
      af[mt] = *(const short8*)&sA[(wrow + mt * 16 + cr) * 40 + gp * 8];
#pragma unroll
    for (int nt = 0; nt < 8; ++nt) {
      short8 bfr = *(const short8*)&sB[(nt * 4 + gp) * 128 + cr * 8];
#pragma unroll
      for (int mt = 0; mt < 3; ++mt)
        acc[mt][nt] = __builtin_amdgcn_mfma_f32_16x16x32_bf16(af[mt], bfr, acc[mt][nt], 0, 0, 0);
    }
    __syncthreads();
  }

  // relu -> sH (bf16)
#pragma unroll
  for (int mt = 0; mt < 3; ++mt)
#pragma unroll
    for (int nt = 0; nt < 8; ++nt)
#pragma unroll
      for (int rr = 0; rr < 4; ++rr)
        sH[(wrow + mt * 16 + gp * 4 + rr) * 136 + nt * 16 + cr] =
            (short)f2bf(fmaxf(acc[mt][nt][rr], 0.f));
  __syncthreads();

  // ---- layer 2: K = 128 ----
  f32x4 acc2[3][8];
#pragma unroll
  for (int mt = 0; mt < 3; ++mt)
#pragma unroll
    for (int nt = 0; nt < 8; ++nt)
      acc2[mt][nt] = (f32x4){bia2[nt], bia2[nt], bia2[nt], bia2[nt]};
  for (int c2 = 0; c2 < 4; ++c2) {
    {
      const short8* wsrc = (const short8*)(W2p + c2 * 4096);
      short8 t0 = wsrc[tid], t1 = wsrc[tid + 256];
      ((short8*)sB)[tid] = t0; ((short8*)sB)[tid + 256] = t1;
    }
    __syncthreads();
    short8 af[3];
#pragma unroll
    for (int mt = 0; mt < 3; ++mt)
      af[mt] = *(const short8*)&sH[(wrow + mt * 16 + cr) * 136 + c2 * 32 + gp * 8];
#pragma unroll
    for (int nt = 0; nt < 8; ++nt) {
      short8 bfr = *(const short8*)&sB[(nt * 4 + gp) * 128 + cr * 8];
#pragma unroll
      for (int mt = 0; mt < 3; ++mt)
        acc2[mt][nt] = __builtin_amdgcn_mfma_f32_16x16x32_bf16(af[mt], bfr, acc2[mt][nt], 0, 0, 0);
    }
    __syncthreads();
  }

  // attention logits from fp32 accumulators (reduce over the 16 col-lanes)
#pragma unroll
  for (int mt = 0; mt < 3; ++mt)
#pragma unroll
    for (int rr = 0; rr < 4; ++rr) {
      float p = 0.f;
#pragma unroll
      for (int nt = 0; nt < 8; ++nt) p += acc2[mt][nt][rr] * aWr[nt];
      p += __shfl_xor(p, 1, 64);
      p += __shfl_xor(p, 2, 64);
      p += __shfl_xor(p, 4, 64);
      p += __shfl_xor(p, 8, 64);
      if (cr == 0) logits[e0 + wrow + mt * 16 + gp * 4 + rr] = p;
    }

  // messages -> sH (bf16) -> coalesced global write
#pragma unroll
  for (int mt = 0; mt < 3; ++mt)
#pragma unroll
    for (int nt = 0; nt < 8; ++nt)
#pragma unroll
      for (int rr = 0; rr < 4; ++rr)
        sH[(wrow + mt * 16 + gp * 4 + rr) * 136 + nt * 16 + cr] =
            (short)f2bf(acc2[mt][nt][rr]);
  __syncthreads();
#pragma unroll
  for (int it = 0; it < 12; ++it) {
    int row = it * 16 + (tid >> 4), o8 = (tid & 15) * 8;
    *(short8*)(msg + (size_t)(e0 + row) * HID + o8) = *(const short8*)&sH[row * 136 + o8];
  }
}

// ---------- node update MLP via MFMA (+ residual), agg read from d_out ----------
__global__ __launch_bounds__(256, 2) void k_node_mfma(
    const float* __restrict__ nf, const float* __restrict__ agg,
    const short* __restrict__ U1p, const float* __restrict__ b1,
    const short* __restrict__ U2p, const float* __restrict__ b2,
    float* __restrict__ out) {
  __shared__ __align__(16) short sA[192 * 40];
  __shared__ __align__(16) short sB[4096];
  __shared__ __align__(16) short sH[192 * 136];

  const int tid = threadIdx.x;
  const int wv = tid >> 6, ln = tid & 63, cr = ln & 15, gp = ln >> 4;
  const int n0 = blockIdx.x * 192;
  const int wrow = wv * 48;

  float bia[8], bia2[8];
#pragma unroll
  for (int nt = 0; nt < 8; ++nt) {
    bia[nt] = b1[nt * 16 + cr];
    bia2[nt] = b2[nt * 16 + cr];
  }
  f32x4 acc[3][8];
#pragma unroll
  for (int mt = 0; mt < 3; ++mt)
#pragma unroll
    for (int nt = 0; nt < 8; ++nt)
      acc[mt][nt] = (f32x4){bia[nt], bia[nt], bia[nt], bia[nt]};

  // layer 1: K = 256 (chunks 0-3: nf, 4-7: agg == d_out; safe: each block reads
  // only its own 192 rows and all reads precede all writes)
  for (int c = 0; c < 8; ++c) {
#pragma unroll
    for (int it = 0; it < 3; ++it) {
      int row = it * 64 + (tid >> 2), k8 = (tid & 3) * 8;
      int n = n0 + row; if (n >= NN) n = NN - 1;
      const float* src = (c < 4) ? nf + (size_t)n * ND + c * 32 + k8
                                 : agg + (size_t)n * ND + (c - 4) * 32 + k8;
      float4 v0 = *(const float4*)src, v1 = *(const float4*)(src + 4);
      short8 s;
      s[0] = (short)f2bf(v0.x); s[1] = (short)f2bf(v0.y);
      s[2] = (short)f2bf(v0.z); s[3] = (short)f2bf(v0.w);
      s[4] = (short)f2bf(v1.x); s[5] = (short)f2bf(v1.y);
      s[6] = (short)f2bf(v1.z); s[7] = (short)f2bf(v1.w);
      *(short8*)&sA[row * 40 + k8] = s;
    }
    {
      const short8* wsrc = (const short8*)(U1p + c * 4096);
      short8 t0 = wsrc[tid], t1 = wsrc[tid + 256];
      ((short8*)sB)[tid] = t0; ((short8*)sB)[tid + 256] = t1;
    }
    __syncthreads();
    short8 af[3];
#pragma unroll
    for (int mt = 0; mt < 3; ++mt)
      af[mt] = *(const short8*)&sA[(wrow + mt * 16 + cr) * 40 + gp * 8];
#pragma unroll
    for (int nt = 0; nt < 8; ++nt) {
      short8 bfr = *(const short8*)&sB[(nt * 4 + gp) * 128 + cr * 8];
#pragma unroll
      for (int mt = 0; mt < 3; ++mt)
        acc[mt][nt] = __builtin_amdgcn_mfma_f32_16x16x32_bf16(af[mt], bfr, acc[mt][nt], 0, 0, 0);
    }
    __syncthreads();
  }

#pragma unroll
  for (int mt = 0; mt < 3; ++mt)
#pragma unroll
    for (int nt = 0; nt < 8; ++nt)
#pragma unroll
      for (int rr = 0; rr < 4; ++rr)
        sH[(wrow + mt * 16 + gp * 4 + rr) * 136 + nt * 16 + cr] =
            (short)f2bf(fmaxf(acc[mt][nt][rr], 0.f));
  __syncthreads();

  f32x4 acc2[3][8];
#pragma unroll
  for (int mt = 0; mt < 3; ++mt)
#pragma unroll
    for (int nt = 0; nt < 8; ++nt)
      acc2[mt][nt] = (f32x4){bia2[nt], bia2[nt], bia2[nt], bia2[nt]};
  for (int c2 = 0; c2 < 4; ++c2) {
    {
      const short8* wsrc = (const short8*)(U2p + c2 * 4096);
      short8 t0 = wsrc[tid], t1 = wsrc[tid + 256];
      ((short8*)sB)[tid] = t0; ((short8*)sB)[tid + 256] = t1;
    }
    __syncthreads();
    short8 af[3];
#pragma unroll
    for (int mt = 0; mt < 3; ++mt)
      af[mt] = *(const short8*)&sH[(wrow + mt * 16 + cr) * 136 + c2 * 32 + gp * 8];
#pragma unroll
    for (int nt = 0; nt < 8; ++nt) {
      short8 bfr = *(const short8*)&sB[(nt * 4 + gp) * 128 + cr * 8];
#pragma unroll
      for (int mt = 0; mt < 3; ++mt)
        acc2[mt][nt] = __builtin_amdgcn_mfma_f32_16x16x32_bf16(af[mt], bfr, acc2[mt][nt], 0, 0, 0);
    }
    __syncthreads();
  }

  // residual + store
#pragma unroll
  for (int mt = 0; mt < 3; ++mt)
#pragma unroll
    for (int rr = 0; rr < 4; ++rr) {
      int n = n0 + wrow + mt * 16 + gp * 4 + rr;
      if (n < NN) {
#pragma unroll
        for (int nt = 0; nt < 8; ++nt) {
          int col = nt * 16 + cr;
          out[(size_t)n * ND + col] = acc2[mt][nt][rr] + nf[(size_t)n * ND + col];
        }
      }
    }
}

// ---------- softmax reductions ----------
__device__ __forceinline__ float block_reduce_max(float m) {
#pragma unroll
  for (int s = 1; s < 64; s <<= 1) m = fmaxf(m, __shfl_xor(m, s, 64));
  __shared__ float sm[4];
  if ((threadIdx.x & 63) == 0) sm[threadIdx.x >> 6] = m;
  __syncthreads();
  return fmaxf(fmaxf(sm[0], sm[1]), fmaxf(sm[2], sm[3]));
}
__device__ __forceinline__ float block_reduce_sum(float v) {
#pragma unroll
  for (int s = 1; s < 64; s <<= 1) v += __shfl_xor(v, s, 64);
  __shared__ float sv[4];
  if ((threadIdx.x & 63) == 0) sv[threadIdx.x >> 6] = v;
  __syncthreads();
  return sv[0] + sv[1] + sv[2] + sv[3];
}

__global__ __launch_bounds__(256) void k_redmax_p(const float* __restrict__ logits,
                                                 float* __restrict__ pmax) {
  float m = -3.402823466e38f;
  for (int i = blockIdx.x * 256 + threadIdx.x; i < NE; i += 1024 * 256)
    m = fmaxf(m, logits[i]);
  m = block_reduce_max(m);
  if (threadIdx.x == 0) pmax[blockIdx.x] = m;
}
__global__ __launch_bounds__(256) void k_redmax_f(const float* __restrict__ p,
                                                 float* __restrict__ red) {
  float m = fmaxf(fmaxf(p[threadIdx.x], p[threadIdx.x + 256]),
                  fmaxf(p[threadIdx.x + 512], p[threadIdx.x + 768]));
  m = block_reduce_max(m);
  if (threadIdx.x == 0) red[0] = m;
}
__global__ __launch_bounds__(256) void k_redsum_p(const float* __restrict__ logits,
                                                 const float* __restrict__ red,
                                                 float* __restrict__ psum) {
  float gm = red[0], s = 0.f;
  for (int i = blockIdx.x * 256 + threadIdx.x; i < NE; i += 1024 * 256)
    s += expf(logits[i] - gm);
  s = block_reduce_sum(s);
  if (threadIdx.x == 0) psum[blockIdx.x] = s;
}
__global__ __launch_bounds__(256) void k_redsum_f(const float* __restrict__ p,
                                                 float* __restrict__ red) {
  float s = p[threadIdx.x] + p[threadIdx.x + 256] + p[threadIdx.x + 512] +
            p[threadIdx.x + 768];
  s = block_reduce_sum(s);
  if (threadIdx.x == 0) red[1] = 1.0f / s;
}

// ---------- attn-weighted scatter-add into d_out ----------
__global__ __launch_bounds__(256) void k_scatter(
    const uint16_t* __restrict__ msg, const float* __restrict__ logits,
    const int* __restrict__ ei, const float* __restrict__ red,
    float* __restrict__ agg) {
  int gid = blockIdx.x * 256 + threadIdx.x;
  int e = gid >> 5, q = (gid & 31) * 4;
  if (e >= NE) return;
  float w = expf(logits[e] - red[0]) * red[1];
  int c = ei[NE + e];
  ushort4 m4 = *(const ushort4*)(msg + (size_t)e * HID + q);
  float* dst = agg + (size_t)c * ND + q;
  atomicAdd(dst + 0, w * bf2f(m4.x));
  atomicAdd(dst + 1, w * bf2f(m4.y));
  atomicAdd(dst + 2, w * bf2f(m4.z));
  atomicAdd(dst + 3, w * bf2f(m4.w));
}

__global__ __launch_bounds__(256) void k_zero(float4* __restrict__ p, int n4) {
  for (int i = blockIdx.x * 256 + threadIdx.x; i < n4; i += gridDim.x * 256)
    p[i] = make_float4(0.f, 0.f, 0.f, 0.f);
}

extern "C" void kernel_launch(void* const* d_in, const int* in_sizes, int n_in,
                              void* d_out, int out_size, void* d_ws, size_t ws_size,
                              hipStream_t stream) {
  const float* nf  = (const float*)d_in[0];
  const float* ef  = (const float*)d_in[1];
  const float* mW1 = (const float*)d_in[2];
  const float* mb1 = (const float*)d_in[3];
  const float* mW2 = (const float*)d_in[4];
  const float* mb2 = (const float*)d_in[5];
  const float* aW  = (const float*)d_in[6];
  // d_in[7] = a_b — unused (softmax is shift-invariant)
  const float* uW1 = (const float*)d_in[8];
  const float* ub1 = (const float*)d_in[9];
  const float* uW2 = (const float*)d_in[10];
  const float* ub2 = (const float*)d_in[11];
  const int*   ei  = (const int*)d_in[12];
  float* out = (float*)d_out;

  // ws layout: msg bf16 [NE*128] | logits f32 [NE] | pmax[1024] | psum[1024] |
  //            red[2] (+pad) | W1p | W2p | U1p | U2p (frag-ordered bf16)
  char* ws = (char*)d_ws;
  uint16_t* msg = (uint16_t*)ws;
  float* logits = (float*)(ws + (size_t)NE * HID * 2);   // byte offset 153600000
  float* pmax = logits + NE;
  float* psum = pmax + 1024;
  float* red  = psum + 1024;
  short* W1p = (short*)(ws + 156008256);
  short* W2p = W1p + 36864;
  short* U1p = W2p + 16384;
  short* U2p = U1p + 32768;

  k_prep<<<400, 256, 0, stream>>>(mW1, mW2, uW1, uW2, W1p, W2p, U1p, U2p);
  k_zero<<<2048, 256, 0, stream>>>((float4*)out, NN * ND / 4);
  k_edge_mfma<<<NE / 192, 256, 0, stream>>>(nf, ef, W1p, mb1, W2p, mb2, aW, ei, msg, logits);
  k_redmax_p<<<1024, 256, 0, stream>>>(logits, pmax);
  k_redmax_f<<<1, 256, 0, stream>>>(pmax, red);
  k_redsum_p<<<1024, 256, 0, stream>>>(logits, red, psum);
  k_redsum_f<<<1, 256, 0, stream>>>(psum, red);
  k_scatter<<<(NE * 32) / 256, 256, 0, stream>>>(msg, logits, ei, red, out);
  k_node_mfma<<<(NN + 191) / 192, 256, 0, stream>>>(nf, out, U1p, ub1, U2p, ub2, out);
}

// Round 5
// 399.104 us; speedup vs baseline: 6.2416x; 3.1462x over previous
//
#include <hip/hip_runtime.h>
#include <hip/hip_bf16.h>
#include <stdint.h>

#define NN 100000
#define NE 600000
#define ND 128
#define ED 32
#define HID 128
#define SCANB 391  // ceil(NN/256)

using short8 = __attribute__((ext_vector_type(8))) short;
using f32x4  = __attribute__((ext_vector_type(4))) float;

// ---------- bf16 helpers (manual RNE, deterministic) ----------
__device__ __forceinline__ uint32_t f2bf(float f) {
  uint32_t u = __float_as_uint(f);
  return (u + 0x7FFFu + ((u >> 16) & 1u)) >> 16;
}
__device__ __forceinline__ float bf2f(uint32_t h) {
  return __uint_as_float(h << 16);
}

// ---------- weight pre-pack: frag-ordered bf16 ----------
__global__ __launch_bounds__(256) void k_prep(
    const float* __restrict__ W1, const float* __restrict__ W2,
    const float* __restrict__ uW1, const float* __restrict__ uW2,
    short* __restrict__ W1p, short* __restrict__ W2p,
    short* __restrict__ U1p, short* __restrict__ U2p) {
  int o = blockIdx.x * 256 + threadIdx.x;
  const float* src; short* dst; int rel;
  if (o < 36864)      { rel = o;         src = W1;  dst = W1p; }
  else if (o < 53248) { rel = o - 36864; src = W2;  dst = W2p; }
  else if (o < 86016) { rel = o - 53248; src = uW1; dst = U1p; }
  else                { rel = o - 86016; src = uW2; dst = U2p; }
  int j = rel & 7, c16 = (rel >> 3) & 15, g = (rel >> 7) & 3, nt = (rel >> 9) & 7, c = rel >> 12;
  int k = c * 32 + g * 8 + j, n = nt * 16 + c16;
  dst[rel] = (short)f2bf(src[k * 128 + n]);
}

// ---------- edge MLP via MFMA: messages (bf16) + attention logits ----------
__global__ __launch_bounds__(256, 2) void k_edge_mfma(
    const float* __restrict__ nf, const float* __restrict__ ef,
    const short* __restrict__ W1p, const float* __restrict__ b1,
    const short* __restrict__ W2p, const float* __restrict__ b2,
    const float* __restrict__ aW, const int* __restrict__ ei,
    uint16_t* __restrict__ msg, float* __restrict__ logits) {
  __shared__ __align__(16) short sA[192 * 40];
  __shared__ __align__(16) short sB[4096];
  __shared__ __align__(16) short sH[192 * 136];
  __shared__ int sIdx[384];

  const int tid = threadIdx.x;
  const int wv = tid >> 6, ln = tid & 63, cr = ln & 15, gp = ln >> 4;
  const int e0 = blockIdx.x * 192;
  const int wrow = wv * 48;

  if (tid < 192) {
    sIdx[tid] = ei[e0 + tid];
    sIdx[192 + tid] = ei[NE + e0 + tid];
  }

  float bia[8], aWr[8], bia2[8];
#pragma unroll
  for (int nt = 0; nt < 8; ++nt) {
    bia[nt] = b1[nt * 16 + cr];
    bia2[nt] = b2[nt * 16 + cr];
    aWr[nt] = aW[nt * 16 + cr];
  }
  f32x4 acc[3][8];
#pragma unroll
  for (int mt = 0; mt < 3; ++mt)
#pragma unroll
    for (int nt = 0; nt < 8; ++nt)
      acc[mt][nt] = (f32x4){bia[nt], bia[nt], bia[nt], bia[nt]};
  __syncthreads();

  // layer 1: K = 288 (chunks 0-3: nf[row], 4-7: nf[col], 8: ef)
  for (int c = 0; c < 9; ++c) {
#pragma unroll
    for (int it = 0; it < 3; ++it) {
      int row = it * 64 + (tid >> 2), k8 = (tid & 3) * 8;
      const float* src;
      if (c < 4)      src = nf + (size_t)sIdx[row] * ND + c * 32 + k8;
      else if (c < 8) src = nf + (size_t)sIdx[192 + row] * ND + (c - 4) * 32 + k8;
      else            src = ef + (size_t)(e0 + row) * ED + k8;
      float4 v0 = *(const float4*)src, v1 = *(const float4*)(src + 4);
      short8 s;
      s[0] = (short)f2bf(v0.x); s[1] = (short)f2bf(v0.y);
      s[2] = (short)f2bf(v0.z); s[3] = (short)f2bf(v0.w);
      s[4] = (short)f2bf(v1.x); s[5] = (short)f2bf(v1.y);
      s[6] = (short)f2bf(v1.z); s[7] = (short)f2bf(v1.w);
      *(short8*)&sA[row * 40 + k8] = s;
    }
    {
      const short8* wsrc = (const short8*)(W1p + c * 4096);
      short8 t0 = wsrc[tid], t1 = wsrc[tid + 256];
      ((short8*)sB)[tid] = t0; ((short8*)sB)[tid + 256] = t1;
    }
    __syncthreads();
    short8 af[3];
#pragma unroll
    for (int mt = 0; mt < 3; ++mt)
      af[mt] = *(const short8*)&sA[(wrow + mt * 16 + cr) * 40 + gp * 8];
#pragma unroll
    for (int nt = 0; nt < 8; ++nt) {
      short8 bfr = *(const short8*)&sB[(nt * 4 + gp) * 128 + cr * 8];
#pragma unroll
      for (int mt = 0; mt < 3; ++mt)
        acc[mt][nt] = __builtin_amdgcn_mfma_f32_16x16x32_bf16(af[mt], bfr, acc[mt][nt], 0, 0, 0);
    }
    __syncthreads();
  }

  // relu -> sH (bf16)
#pragma unroll
  for (int mt = 0; mt < 3; ++mt)
#pragma unroll
    for (int nt = 0; nt < 8; ++nt)
#pragma unroll
      for (int rr = 0; rr < 4; ++rr)
        sH[(wrow + mt * 16 + gp * 4 + rr) * 136 + nt * 16 + cr] =
            (short)f2bf(fmaxf(acc[mt][nt][rr], 0.f));
  __syncthreads();

  // layer 2: K = 128
  f32x4 acc2[3][8];
#pragma unroll
  for (int mt = 0; mt < 3; ++mt)
#pragma unroll
    for (int nt = 0; nt < 8; ++nt)
      acc2[mt][nt] = (f32x4){bia2[nt], bia2[nt], bia2[nt], bia2[nt]};
  for (int c2 = 0; c2 < 4; ++c2) {
    {
      const short8* wsrc = (const short8*)(W2p + c2 * 4096);
      short8 t0 = wsrc[tid], t1 = wsrc[tid + 256];
      ((short8*)sB)[tid] = t0; ((short8*)sB)[tid + 256] = t1;
    }
    __syncthreads();
    short8 af[3];
#pragma unroll
    for (int mt = 0; mt < 3; ++mt)
      af[mt] = *(const short8*)&sH[(wrow + mt * 16 + cr) * 136 + c2 * 32 + gp * 8];
#pragma unroll
    for (int nt = 0; nt < 8; ++nt) {
      short8 bfr = *(const short8*)&sB[(nt * 4 + gp) * 128 + cr * 8];
#pragma unroll
      for (int mt = 0; mt < 3; ++mt)
        acc2[mt][nt] = __builtin_amdgcn_mfma_f32_16x16x32_bf16(af[mt], bfr, acc2[mt][nt], 0, 0, 0);
    }
    __syncthreads();
  }

  // attention logits (reduce over the 16 col-lanes)
#pragma unroll
  for (int mt = 0; mt < 3; ++mt)
#pragma unroll
    for (int rr = 0; rr < 4; ++rr) {
      float p = 0.f;
#pragma unroll
      for (int nt = 0; nt < 8; ++nt) p += acc2[mt][nt][rr] * aWr[nt];
      p += __shfl_xor(p, 1, 64);
      p += __shfl_xor(p, 2, 64);
      p += __shfl_xor(p, 4, 64);
      p += __shfl_xor(p, 8, 64);
      if (cr == 0) logits[e0 + wrow + mt * 16 + gp * 4 + rr] = p;
    }

  // messages -> sH (bf16) -> coalesced global write
#pragma unroll
  for (int mt = 0; mt < 3; ++mt)
#pragma unroll
    for (int nt = 0; nt < 8; ++nt)
#pragma unroll
      for (int rr = 0; rr < 4; ++rr)
        sH[(wrow + mt * 16 + gp * 4 + rr) * 136 + nt * 16 + cr] =
            (short)f2bf(acc2[mt][nt][rr]);
  __syncthreads();
#pragma unroll
  for (int it = 0; it < 12; ++it) {
    int row = it * 16 + (tid >> 4), o8 = (tid & 15) * 8;
    *(short8*)(msg + (size_t)(e0 + row) * HID + o8) = *(const short8*)&sH[row * 136 + o8];
  }
}

// ---------- node update MLP via MFMA (+ residual) ----------
__global__ __launch_bounds__(256, 2) void k_node_mfma(
    const float* __restrict__ nf, const float* __restrict__ agg,
    const short* __restrict__ U1p, const float* __restrict__ b1,
    const short* __restrict__ U2p, const float* __restrict__ b2,
    float* __restrict__ out) {
  __shared__ __align__(16) short sA[192 * 40];
  __shared__ __align__(16) short sB[4096];
  __shared__ __align__(16) short sH[192 * 136];

  const int tid = threadIdx.x;
  const int wv = tid >> 6, ln = tid & 63, cr = ln & 15, gp = ln >> 4;
  const int n0 = blockIdx.x * 192;
  const int wrow = wv * 48;

  float bia[8], bia2[8];
#pragma unroll
  for (int nt = 0; nt < 8; ++nt) {
    bia[nt] = b1[nt * 16 + cr];
    bia2[nt] = b2[nt * 16 + cr];
  }
  f32x4 acc[3][8];
#pragma unroll
  for (int mt = 0; mt < 3; ++mt)
#pragma unroll
    for (int nt = 0; nt < 8; ++nt)
      acc[mt][nt] = (f32x4){bia[nt], bia[nt], bia[nt], bia[nt]};

  // layer 1: K = 256 (chunks 0-3: nf, 4-7: agg == d_out; block-local rows,
  // all reads precede all writes)
  for (int c = 0; c < 8; ++c) {
#pragma unroll
    for (int it = 0; it < 3; ++it) {
      int row = it * 64 + (tid >> 2), k8 = (tid & 3) * 8;
      int n = n0 + row; if (n >= NN) n = NN - 1;
      const float* src = (c < 4) ? nf + (size_t)n * ND + c * 32 + k8
                                 : agg + (size_t)n * ND + (c - 4) * 32 + k8;
      float4 v0 = *(const float4*)src, v1 = *(const float4*)(src + 4);
      short8 s;
      s[0] = (short)f2bf(v0.x); s[1] = (short)f2bf(v0.y);
      s[2] = (short)f2bf(v0.z); s[3] = (short)f2bf(v0.w);
      s[4] = (short)f2bf(v1.x); s[5] = (short)f2bf(v1.y);
      s[6] = (short)f2bf(v1.z); s[7] = (short)f2bf(v1.w);
      *(short8*)&sA[row * 40 + k8] = s;
    }
    {
      const short8* wsrc = (const short8*)(U1p + c * 4096);
      short8 t0 = wsrc[tid], t1 = wsrc[tid + 256];
      ((short8*)sB)[tid] = t0; ((short8*)sB)[tid + 256] = t1;
    }
    __syncthreads();
    short8 af[3];
#pragma unroll
    for (int mt = 0; mt < 3; ++mt)
      af[mt] = *(const short8*)&sA[(wrow + mt * 16 + cr) * 40 + gp * 8];
#pragma unroll
    for (int nt = 0; nt < 8; ++nt) {
      short8 bfr = *(const short8*)&sB[(nt * 4 + gp) * 128 + cr * 8];
#pragma unroll
      for (int mt = 0; mt < 3; ++mt)
        acc[mt][nt] = __builtin_amdgcn_mfma_f32_16x16x32_bf16(af[mt], bfr, acc[mt][nt], 0, 0, 0);
    }
    __syncthreads();
  }

#pragma unroll
  for (int mt = 0; mt < 3; ++mt)
#pragma unroll
    for (int nt = 0; nt < 8; ++nt)
#pragma unroll
      for (int rr = 0; rr < 4; ++rr)
        sH[(wrow + mt * 16 + gp * 4 + rr) * 136 + nt * 16 + cr] =
            (short)f2bf(fmaxf(acc[mt][nt][rr], 0.f));
  __syncthreads();

  f32x4 acc2[3][8];
#pragma unroll
  for (int mt = 0; mt < 3; ++mt)
#pragma unroll
    for (int nt = 0; nt < 8; ++nt)
      acc2[mt][nt] = (f32x4){bia2[nt], bia2[nt], bia2[nt], bia2[nt]};
  for (int c2 = 0; c2 < 4; ++c2) {
    {
      const short8* wsrc = (const short8*)(U2p + c2 * 4096);
      short8 t0 = wsrc[tid], t1 = wsrc[tid + 256];
      ((short8*)sB)[tid] = t0; ((short8*)sB)[tid + 256] = t1;
    }
    __syncthreads();
    short8 af[3];
#pragma unroll
    for (int mt = 0; mt < 3; ++mt)
      af[mt] = *(const short8*)&sH[(wrow + mt * 16 + cr) * 136 + c2 * 32 + gp * 8];
#pragma unroll
    for (int nt = 0; nt < 8; ++nt) {
      short8 bfr = *(const short8*)&sB[(nt * 4 + gp) * 128 + cr * 8];
#pragma unroll
      for (int mt = 0; mt < 3; ++mt)
        acc2[mt][nt] = __builtin_amdgcn_mfma_f32_16x16x32_bf16(af[mt], bfr, acc2[mt][nt], 0, 0, 0);
    }
    __syncthreads();
  }

#pragma unroll
  for (int mt = 0; mt < 3; ++mt)
#pragma unroll
    for (int rr = 0; rr < 4; ++rr) {
      int n = n0 + wrow + mt * 16 + gp * 4 + rr;
      if (n < NN) {
#pragma unroll
        for (int nt = 0; nt < 8; ++nt) {
          int col = nt * 16 + cr;
          out[(size_t)n * ND + col] = acc2[mt][nt][rr] + nf[(size_t)n * ND + col];
        }
      }
    }
}

// ---------- softmax reductions ----------
__device__ __forceinline__ float block_reduce_max(float m) {
#pragma unroll
  for (int s = 1; s < 64; s <<= 1) m = fmaxf(m, __shfl_xor(m, s, 64));
  __shared__ float sm[4];
  if ((threadIdx.x & 63) == 0) sm[threadIdx.x >> 6] = m;
  __syncthreads();
  return fmaxf(fmaxf(sm[0], sm[1]), fmaxf(sm[2], sm[3]));
}
__device__ __forceinline__ float block_reduce_sum(float v) {
#pragma unroll
  for (int s = 1; s < 64; s <<= 1) v += __shfl_xor(v, s, 64);
  __shared__ float sv[4];
  if ((threadIdx.x & 63) == 0) sv[threadIdx.x >> 6] = v;
  __syncthreads();
  return sv[0] + sv[1] + sv[2] + sv[3];
}

__global__ __launch_bounds__(256) void k_redmax_p(const float* __restrict__ logits,
                                                 float* __restrict__ pmax) {
  float m = -3.402823466e38f;
  for (int i = blockIdx.x * 256 + threadIdx.x; i < NE; i += 1024 * 256)
    m = fmaxf(m, logits[i]);
  m = block_reduce_max(m);
  if (threadIdx.x == 0) pmax[blockIdx.x] = m;
}
__global__ __launch_bounds__(256) void k_redmax_f(const float* __restrict__ p,
                                                 float* __restrict__ red) {
  float m = fmaxf(fmaxf(p[threadIdx.x], p[threadIdx.x + 256]),
                  fmaxf(p[threadIdx.x + 512], p[threadIdx.x + 768]));
  m = block_reduce_max(m);
  if (threadIdx.x == 0) red[0] = m;
}
__global__ __launch_bounds__(256) void k_redsum_p(const float* __restrict__ logits,
                                                 const float* __restrict__ red,
                                                 float* __restrict__ psum) {
  float gm = red[0], s = 0.f;
  for (int i = blockIdx.x * 256 + threadIdx.x; i < NE; i += 1024 * 256)
    s += expf(logits[i] - gm);
  s = block_reduce_sum(s);
  if (threadIdx.x == 0) psum[blockIdx.x] = s;
}
__global__ __launch_bounds__(256) void k_redsum_f(const float* __restrict__ p,
                                                 float* __restrict__ red) {
  float s = p[threadIdx.x] + p[threadIdx.x + 256] + p[threadIdx.x + 512] +
            p[threadIdx.x + 768];
  s = block_reduce_sum(s);
  if (threadIdx.x == 0) red[1] = 1.0f / s;
}

// logits -> softmax weights in place
__global__ __launch_bounds__(256) void k_weights(float* __restrict__ logits,
                                                 const float* __restrict__ red) {
  int e = blockIdx.x * 256 + threadIdx.x;
  if (e < NE) logits[e] = expf(logits[e] - red[0]) * red[1];
}

// ---------- CSR build ----------
__global__ __launch_bounds__(256) void k_zero_cnt(int* __restrict__ cnt) {
  int i = blockIdx.x * 256 + threadIdx.x;
  if (i < NN) cnt[i] = 0;
}
__global__ __launch_bounds__(256) void k_hist(const int* __restrict__ ei,
                                              int* __restrict__ cnt) {
  int e = blockIdx.x * 256 + threadIdx.x;
  if (e < NE) atomicAdd(&cnt[ei[NE + e]], 1);
}
__global__ __launch_bounds__(256) void k_scan_bsum(const int* __restrict__ cnt,
                                                   int* __restrict__ bsum) {
  int i = blockIdx.x * 256 + threadIdx.x;
  int v = (i < NN) ? cnt[i] : 0;
#pragma unroll
  for (int s = 1; s < 64; s <<= 1) v += __shfl_xor(v, s, 64);
  __shared__ int sv[4];
  if ((threadIdx.x & 63) == 0) sv[threadIdx.x >> 6] = v;
  __syncthreads();
  if (threadIdx.x == 0) bsum[blockIdx.x] = sv[0] + sv[1] + sv[2] + sv[3];
}
__global__ __launch_bounds__(512) void k_scan_boff(const int* __restrict__ bsum,
                                                   int* __restrict__ boff,
                                                   int* __restrict__ rowptr) {
  __shared__ int s[512];
  int t = threadIdx.x;
  int v = (t < SCANB) ? bsum[t] : 0;
  s[t] = v;
  __syncthreads();
  for (int off = 1; off < 512; off <<= 1) {
    int u = (t >= off) ? s[t - off] : 0;
    __syncthreads();
    s[t] += u;
    __syncthreads();
  }
  if (t < SCANB) boff[t] = s[t] - v;  // exclusive
  if (t == 0) rowptr[NN] = NE;
}
// exclusive scan within each 256-block + boff; writes rowptr and cursor (cnt reused)
__global__ __launch_bounds__(256) void k_scan_final(int* __restrict__ cnt,
                                                    const int* __restrict__ boff,
                                                    int* __restrict__ rowptr) {
  __shared__ int s[256];
  int b = blockIdx.x, t = threadIdx.x, i = b * 256 + t;
  int v = (i < NN) ? cnt[i] : 0;
  s[t] = v;
  __syncthreads();
  for (int off = 1; off < 256; off <<= 1) {
    int u = (t >= off) ? s[t - off] : 0;
    __syncthreads();
    s[t] += u;
    __syncthreads();
  }
  int excl = s[t] - v + boff[b];
  if (i < NN) { rowptr[i] = excl; cnt[i] = excl; }  // cnt becomes the fill cursor
}
__global__ __launch_bounds__(256) void k_fill(const int* __restrict__ ei,
                                              int* __restrict__ cursor,
                                              int* __restrict__ eid) {
  int e = blockIdx.x * 256 + threadIdx.x;
  if (e >= NE) return;
  int c = ei[NE + e];
  int pos = atomicAdd(&cursor[c], 1);
  eid[pos] = e;
}

// ---------- CSR gather-aggregate: one wave per node, 2 cols/lane ----------
__global__ __launch_bounds__(256) void k_agg(
    const uint16_t* __restrict__ msg, const float* __restrict__ w,
    const int* __restrict__ rowptr, const int* __restrict__ eid,
    float* __restrict__ out) {
  int n = blockIdx.x * 4 + (threadIdx.x >> 6);
  int lane = threadIdx.x & 63;
  if (n >= NN) return;
  int i0 = rowptr[n], i1 = rowptr[n + 1];
  float a0 = 0.f, a1 = 0.f;
  for (int i = i0; i < i1; ++i) {
    int e = eid[i];
    float wt = w[e];
    uint32_t pk = *(const uint32_t*)(msg + (size_t)e * HID + lane * 2);
    a0 += wt * __uint_as_float(pk << 16);
    a1 += wt * __uint_as_float(pk & 0xFFFF0000u);
  }
  *(float2*)(out + (size_t)n * ND + lane * 2) = make_float2(a0, a1);
}

extern "C" void kernel_launch(void* const* d_in, const int* in_sizes, int n_in,
                              void* d_out, int out_size, void* d_ws, size_t ws_size,
                              hipStream_t stream) {
  const float* nf  = (const float*)d_in[0];
  const float* ef  = (const float*)d_in[1];
  const float* mW1 = (const float*)d_in[2];
  const float* mb1 = (const float*)d_in[3];
  const float* mW2 = (const float*)d_in[4];
  const float* mb2 = (const float*)d_in[5];
  const float* aW  = (const float*)d_in[6];
  // d_in[7] = a_b — unused (softmax is shift-invariant)
  const float* uW1 = (const float*)d_in[8];
  const float* ub1 = (const float*)d_in[9];
  const float* uW2 = (const float*)d_in[10];
  const float* ub2 = (const float*)d_in[11];
  const int*   ei  = (const int*)d_in[12];
  float* out = (float*)d_out;

  // ws layout (bytes):
  //   0          msg bf16 [NE*128]            153,600,000
  //   153600000  logits/weights f32 [NE]        2,400,000
  //   156000000  pmax[1024] psum[1024] red          8,256
  //   156008256  W1p/W2p/U1p/U2p packed bf16      204,800
  //   156213056  rowptr[NN+1] cnt[NN] eid[NE] bsum/boff  ~3.2MB  -> total ~159.4MB
  char* ws = (char*)d_ws;
  uint16_t* msg = (uint16_t*)ws;
  float* logits = (float*)(ws + 153600000);
  float* pmax = (float*)(ws + 156000000);
  float* psum = pmax + 1024;
  float* red  = psum + 1024;
  short* W1p = (short*)(ws + 156008256);
  short* W2p = W1p + 36864;
  short* U1p = W2p + 16384;
  short* U2p = U1p + 32768;
  int* rowptr = (int*)(ws + 156213056);
  int* cnt    = rowptr + (NN + 1);
  int* eid    = cnt + NN;
  int* bsum   = eid + NE;
  int* boff   = bsum + 512;

  k_prep<<<400, 256, 0, stream>>>(mW1, mW2, uW1, uW2, W1p, W2p, U1p, U2p);
  k_zero_cnt<<<SCANB, 256, 0, stream>>>(cnt);
  k_hist<<<(NE + 255) / 256, 256, 0, stream>>>(ei, cnt);
  k_scan_bsum<<<SCANB, 256, 0, stream>>>(cnt, bsum);
  k_scan_boff<<<1, 512, 0, stream>>>(bsum, boff, rowptr);
  k_scan_final<<<SCANB, 256, 0, stream>>>(cnt, boff, rowptr);
  k_fill<<<(NE + 255) / 256, 256, 0, stream>>>(ei, cnt, eid);
  k_edge_mfma<<<NE / 192, 256, 0, stream>>>(nf, ef, W1p, mb1, W2p, mb2, aW, ei, msg, logits);
  k_redmax_p<<<1024, 256, 0, stream>>>(logits, pmax);
  k_redmax_f<<<1, 256, 0, stream>>>(pmax, red);
  k_redsum_p<<<1024, 256, 0, stream>>>(logits, red, psum);
  k_redsum_f<<<1, 256, 0, stream>>>(psum, red);
  k_weights<<<(NE + 255) / 256, 256, 0, stream>>>(logits, red);
  k_agg<<<(NN + 3) / 4, 256, 0, stream>>>(msg, logits, rowptr, eid, out);
  k_node_mfma<<<(NN + 191) / 192, 256, 0, stream>>>(nf, out, U1p, ub1, U2p, ub2, out);
}